// Round 1
// baseline (129.404 us; speedup 1.0000x reference)
//
#include <hip/hip_runtime.h>
#include <math.h>

#define HW (512*512)
#define TS 64
#define HR 70    // tile + 2*3 halo
#define LSTR 72  // padded LDS row stride (multiple of 4)

// ---------------- Kernel 1: per-plane partial sums (global avg pool) ----------------
__global__ __launch_bounds__(256) void k_reduce(const float* __restrict__ x,
                                                float* __restrict__ ws) {
    int bid = blockIdx.x;            // 1024 blocks = 128 planes * 8 chunks
    int plane = bid >> 3, j = bid & 7;
    const float4* xv = (const float4*)x + (size_t)plane * 65536 + (size_t)j * 8192;
    int tid = threadIdx.x;
    float s = 0.f;
    #pragma unroll
    for (int k = 0; k < 32; ++k) {
        float4 v = xv[(size_t)k * 256 + tid];
        s += (v.x + v.y) + (v.z + v.w);
    }
    #pragma unroll
    for (int off = 32; off > 0; off >>= 1) s += __shfl_down(s, off, 64);
    __shared__ float red[4];
    if ((tid & 63) == 0) red[tid >> 6] = s;
    __syncthreads();
    if (tid == 0) ws[bid] = (red[0] + red[1]) + (red[2] + red[3]);
}

// ---------------- Kernel 2: finish pool + channel-attention MLP ----------------
__global__ __launch_bounds__(128) void k_mlp(const float* __restrict__ part,
                                             const float* __restrict__ w1,
                                             const float* __restrict__ b1,
                                             const float* __restrict__ w2,
                                             const float* __restrict__ b2,
                                             float* __restrict__ att_out) {
    __shared__ float pool[128];   // [b][c], b=32, c=4
    __shared__ float hbuf[64];    // [b][r], r=2
    int tid = threadIdx.x;
    float s = 0.f;
    #pragma unroll
    for (int j = 0; j < 8; ++j) s += part[tid * 8 + j];
    pool[tid] = s * (1.f / 262144.f);
    __syncthreads();
    if (tid < 64) {
        int b = tid >> 1, r = tid & 1;
        float h = b1[r];
        #pragma unroll
        for (int c = 0; c < 4; ++c) h += w1[r * 4 + c] * pool[b * 4 + c];
        hbuf[tid] = fmaxf(h, 0.f);          // hbuf[b*2+r]
    }
    __syncthreads();
    {
        int b = tid >> 2, c = tid & 3;
        float z = b2[c];
        #pragma unroll
        for (int r = 0; r < 2; ++r) z += w2[c * 2 + r] * hbuf[b * 2 + r];
        att_out[tid] = 1.f / (1.f + expf(-z));   // att[b*4+c]
    }
}

// ---------------- Kernel 3: fused gate + 1x1 conv + 7x7 conv + sigmoid gate ----------------
__global__ __launch_bounds__(256) void k_fused(const float* __restrict__ x,
                                               const float* __restrict__ conv_w,
                                               const float* __restrict__ conv_b,
                                               const float* __restrict__ sa_w,
                                               const float* __restrict__ sa_b,
                                               const float* __restrict__ att,
                                               float* __restrict__ out) {
    __shared__ float s_out[3 * HR * LSTR];   // out tile+halo, 3 channels
    __shared__ float sw[147];                // sa_w [3][7][7]
    __shared__ float kw[12];                 // conv_w * att(b,c)
    __shared__ float kb[3];
    int tid = threadIdx.x;
    int b = blockIdx.z;
    int ty0 = blockIdx.y * TS, tx0 = blockIdx.x * TS;

    if (tid < 147) sw[tid] = sa_w[tid];
    if (tid >= 160 && tid < 172) {
        int t = tid - 160;                   // t = o*4 + c
        kw[t] = conv_w[t] * att[b * 4 + (t & 3)];
    }
    if (tid >= 192 && tid < 195) kb[tid - 192] = conv_b[tid - 192];
    __syncthreads();

    // Stage: compute gated 1x1-conv output for tile+halo into LDS (0 outside image)
    const float* xb = x + (size_t)b * 4 * HW;
    for (int idx = tid; idx < HR * HR; idx += 256) {
        int r = idx / HR, c = idx - r * HR;
        int gy = ty0 - 3 + r, gx = tx0 - 3 + c;
        float o0 = 0.f, o1 = 0.f, o2 = 0.f;
        if (gy >= 0 && gy < 512 && gx >= 0 && gx < 512) {
            size_t off = (size_t)gy * 512 + gx;
            float x0 = xb[off], x1 = xb[HW + off], x2 = xb[2 * HW + off], x3 = xb[3 * HW + off];
            o0 = kb[0] + kw[0] * x0 + kw[1] * x1 + kw[2]  * x2 + kw[3]  * x3;
            o1 = kb[1] + kw[4] * x0 + kw[5] * x1 + kw[6]  * x2 + kw[7]  * x3;
            o2 = kb[2] + kw[8] * x0 + kw[9] * x1 + kw[10] * x2 + kw[11] * x3;
        }
        s_out[0 * HR * LSTR + r * LSTR + c] = o0;
        s_out[1 * HR * LSTR + r * LSTR + c] = o1;
        s_out[2 * HR * LSTR + r * LSTR + c] = o2;
    }
    __syncthreads();

    // 7x7 conv: each thread owns a 16-row column strip; vertical register reuse
    int tx = tid & 63;
    int r0 = (tid >> 6) * 16;
    float acc[16];
    #pragma unroll
    for (int i = 0; i < 16; ++i) acc[i] = 0.f;

    #pragma unroll
    for (int ch = 0; ch < 3; ++ch) {
        const float* sbase = &s_out[ch * HR * LSTR];
        #pragma unroll
        for (int dx = 0; dx < 7; ++dx) {
            float wt[7];
            #pragma unroll
            for (int dy = 0; dy < 7; ++dy) wt[dy] = sw[ch * 49 + dy * 7 + dx];
            #pragma unroll
            for (int k = 0; k < 22; ++k) {
                float v = sbase[(r0 + k) * LSTR + tx + dx];
                #pragma unroll
                for (int dy = 0; dy < 7; ++dy) {
                    int i = k - dy;
                    if (i >= 0 && i < 16) acc[i] += wt[dy] * v;
                }
            }
        }
    }

    float sb = sa_b[0];
    float* ob = out + (size_t)b * 3 * HW;
    #pragma unroll
    for (int i = 0; i < 16; ++i) {
        float z = acc[i] + sb;
        float satt = 1.f / (1.f + expf(-z));
        int gy = ty0 + r0 + i, gx = tx0 + tx;
        size_t off = (size_t)gy * 512 + gx;
        ob[off]          = s_out[0 * HR * LSTR + (r0 + i + 3) * LSTR + tx + 3] * satt;
        ob[HW + off]     = s_out[1 * HR * LSTR + (r0 + i + 3) * LSTR + tx + 3] * satt;
        ob[2 * HW + off] = s_out[2 * HR * LSTR + (r0 + i + 3) * LSTR + tx + 3] * satt;
    }
}

extern "C" void kernel_launch(void* const* d_in, const int* in_sizes, int n_in,
                              void* d_out, int out_size, void* d_ws, size_t ws_size,
                              hipStream_t stream) {
    const float* x      = (const float*)d_in[0];
    const float* ca_w1  = (const float*)d_in[1];
    const float* ca_b1  = (const float*)d_in[2];
    const float* ca_w2  = (const float*)d_in[3];
    const float* ca_b2  = (const float*)d_in[4];
    const float* conv_w = (const float*)d_in[5];
    const float* conv_b = (const float*)d_in[6];
    const float* sa_w   = (const float*)d_in[7];
    const float* sa_b   = (const float*)d_in[8];
    float* ws  = (float*)d_ws;
    float* out = (float*)d_out;

    hipLaunchKernelGGL(k_reduce, dim3(1024), dim3(256), 0, stream, x, ws);
    hipLaunchKernelGGL(k_mlp, dim3(1), dim3(128), 0, stream,
                       ws, ca_w1, ca_b1, ca_w2, ca_b2, ws + 1024);
    hipLaunchKernelGGL(k_fused, dim3(8, 8, 32), dim3(256), 0, stream,
                       x, conv_w, conv_b, sa_w, sa_b, ws + 1024, out);
}